// Round 1
// baseline (1236.869 us; speedup 1.0000x reference)
//
#include <hip/hip_runtime.h>

// ---------------- CSR build ----------------

__global__ void hist_kernel(const int* __restrict__ dst, int E, int* __restrict__ deg){
    int e = blockIdx.x*256 + threadIdx.x;
    if(e < E) atomicAdd(&deg[dst[e]], 1);
}

__global__ void scan_part(const int* __restrict__ deg, int n, int* __restrict__ partials){
    __shared__ int sm[256];
    int t = threadIdx.x;
    int idx = blockIdx.x*256 + t;
    sm[t] = (idx < n) ? deg[idx] : 0;
    __syncthreads();
    for(int s = 128; s > 0; s >>= 1){ if(t < s) sm[t] += sm[t+s]; __syncthreads(); }
    if(t == 0) partials[blockIdx.x] = sm[0];
}

__global__ void scan_partials_k(int* __restrict__ partials, int nb){
    __shared__ int sm[512];
    int t = threadIdx.x;
    int orig = (t < nb) ? partials[t] : 0;
    sm[t] = orig; __syncthreads();
    for(int s = 1; s < 512; s <<= 1){
        int add = (t >= s) ? sm[t-s] : 0;
        __syncthreads();
        sm[t] += add;
        __syncthreads();
    }
    if(t < nb) partials[t] = sm[t] - orig;   // exclusive
}

__global__ void scan_final(const int* __restrict__ deg, int n,
                           const int* __restrict__ partials, int* __restrict__ row_start){
    __shared__ int sm[256];
    int t = threadIdx.x;
    int idx = blockIdx.x*256 + t;
    int orig = (idx < n) ? deg[idx] : 0;
    sm[t] = orig; __syncthreads();
    for(int s = 1; s < 256; s <<= 1){
        int add = (t >= s) ? sm[t-s] : 0;
        __syncthreads();
        sm[t] += add;
        __syncthreads();
    }
    int excl = partials[blockIdx.x] + sm[t] - orig;
    if(idx < n) row_start[idx] = excl;
    if(idx == n-1) row_start[n] = excl + orig;   // == E
}

__global__ void dinv_kernel(const int* __restrict__ deg, float* __restrict__ dinv, int n){
    int i = blockIdx.x*256 + threadIdx.x;
    if(i < n) dinv[i] = rsqrtf((float)deg[i] + 1.0f);
}

__global__ void fill_csr(const int* __restrict__ src, const int* __restrict__ dst, int E,
                         const int* __restrict__ row_start, int* __restrict__ cursor,
                         int* __restrict__ csr_src){
    int e = blockIdx.x*256 + threadIdx.x;
    if(e < E){
        int d = dst[e];
        int p = atomicAdd(&cursor[d], 1);
        csr_src[row_start[d] + p] = src[e];
    }
}

// ---------------- GEMM: out[n,128] = in[n,128] @ W[128,128] (+bias)(+acc)(*dinv_row) ----------------

template<bool SCALE, bool ACC, bool BIAS>
__global__ __launch_bounds__(256) void gemm128(const float* __restrict__ in, const float* __restrict__ W,
                                               const float* __restrict__ bias, const float* __restrict__ dinv,
                                               float* __restrict__ out, int n){
    __shared__ float Ws[128*128];
    __shared__ float As[16*128];
    int t = threadIdx.x;
    int r0 = blockIdx.x*16;
    if(r0 >= n) return;

    const float4* W4 = (const float4*)W;
    float4* Ws4 = (float4*)Ws;
    #pragma unroll
    for(int i = 0; i < 16; ++i) Ws4[t + i*256] = W4[t + i*256];

    const float4* in4 = (const float4*)(in + (size_t)r0*128);
    float4* As4 = (float4*)As;
    As4[t]       = in4[t];
    As4[t + 256] = in4[t + 256];
    __syncthreads();

    int c  = t & 127;
    int rg = t >> 7;      // 0 or 1 -> rows rg*8 .. rg*8+7
    float acc[8] = {0,0,0,0,0,0,0,0};

    for(int k = 0; k < 128; k += 4){
        float4 a[8];
        #pragma unroll
        for(int r = 0; r < 8; ++r) a[r] = *(const float4*)&As[(rg*8 + r)*128 + k];
        #pragma unroll
        for(int kk = 0; kk < 4; ++kk){
            float wv = Ws[(k+kk)*128 + c];
            #pragma unroll
            for(int r = 0; r < 8; ++r){
                float av = (kk==0)?a[r].x : (kk==1)?a[r].y : (kk==2)?a[r].z : a[r].w;
                acc[r] = fmaf(av, wv, acc[r]);
            }
        }
    }

    #pragma unroll
    for(int r = 0; r < 8; ++r){
        int row = r0 + rg*8 + r;
        float v = acc[r];
        if(BIAS) v += bias[c];
        if(SCALE) v *= dinv[row];
        if(ACC) v += out[(size_t)row*128 + c];
        out[(size_t)row*128 + c] = v;
    }
}

// ---------------- pull aggregation: h[n] = relu(dinv[n]*(y[n] + sum_src y[src]) + b) ----------------

__global__ __launch_bounds__(256) void aggregate(const float* __restrict__ y, const int* __restrict__ row_start,
                                                 const int* __restrict__ csr_src, const float* __restrict__ dinv,
                                                 const float* __restrict__ bias, float* __restrict__ hout, int n){
    int wave = threadIdx.x >> 6;
    int lane = threadIdx.x & 63;
    int node = blockIdx.x*4 + wave;
    if(node >= n) return;
    int s0 = row_start[node];
    int s1 = row_start[node+1];
    float2 acc = *(const float2*)&y[(size_t)node*128 + lane*2];   // self term (already *dinv[node])
    for(int j = s0; j < s1; ++j){
        int s = csr_src[j];
        float2 v = *(const float2*)&y[(size_t)s*128 + lane*2];
        acc.x += v.x; acc.y += v.y;
    }
    float dn = dinv[node];
    float2 b2 = *(const float2*)&bias[lane*2];
    float2 r;
    r.x = fmaxf(fmaf(acc.x, dn, b2.x), 0.f);
    r.y = fmaxf(fmaf(acc.y, dn, b2.y), 0.f);
    *(float2*)&hout[(size_t)node*128 + lane*2] = r;
}

// ---------------- pooling over sorted batch ----------------

__global__ void pool_kernel(const float* __restrict__ hjk, const int* __restrict__ batch,
                            int n, float* __restrict__ pooled){
    int c = threadIdx.x;          // 128 threads = columns
    int base = blockIdx.x*128;
    int end = base + 128; if(end > n) end = n;
    float acc = 0.f; int cur = -1;
    for(int i = base; i < end; ++i){
        int g = batch[i];
        if(g != cur){
            if(cur >= 0) atomicAdd(&pooled[cur*128 + c], acc);
            cur = g; acc = 0.f;
        }
        acc += hjk[(size_t)i*128 + c];
    }
    if(cur >= 0) atomicAdd(&pooled[cur*128 + c], acc);
}

// ---------------- MLP head ----------------

__global__ void head_kernel(const float* __restrict__ pooled,
                            const float* __restrict__ Wm1, const float* __restrict__ bm1,
                            const float* __restrict__ Wm2, const float* __restrict__ bm2,
                            float* __restrict__ out){
    __shared__ float p[128];
    __shared__ float tq[128];
    int g = blockIdx.x, j = threadIdx.x;
    p[j] = pooled[g*128 + j];
    __syncthreads();
    float a = bm1[j];
    for(int k = 0; k < 128; ++k) a = fmaf(p[k], Wm1[k*128 + j], a);
    tq[j] = fmaxf(a, 0.f);
    __syncthreads();
    if(j < 10){
        float o = bm2[j];
        for(int k = 0; k < 128; ++k) o = fmaf(tq[k], Wm2[k*10 + j], o);
        out[g*10 + j] = o;
    }
}

// ---------------- launch ----------------

extern "C" void kernel_launch(void* const* d_in, const int* in_sizes, int n_in,
                              void* d_out, int out_size, void* d_ws, size_t ws_size,
                              hipStream_t stream){
    const float* x    = (const float*)d_in[0];
    const int*   ei   = (const int*)  d_in[1];
    const int*   batch= (const int*)  d_in[2];
    const float* W0   = (const float*)d_in[3];
    const float* b0   = (const float*)d_in[4];
    const float* W1   = (const float*)d_in[5];
    const float* b1   = (const float*)d_in[6];
    const float* W2   = (const float*)d_in[7];
    const float* b2   = (const float*)d_in[8];
    const float* Wjk  = (const float*)d_in[9];
    const float* bjk  = (const float*)d_in[10];
    const float* Wm1  = (const float*)d_in[11];
    const float* bm1  = (const float*)d_in[12];
    const float* Wm2  = (const float*)d_in[13];
    const float* bm2  = (const float*)d_in[14];

    const int N = in_sizes[0] / 128;
    const int E = in_sizes[1] / 2;
    const int* src = ei;
    const int* dst = ei + E;

    char* ws = (char*)d_ws;
    size_t off = 0;
    auto take = [&](size_t bytes)->char*{
        char* p = ws + off; off = (off + bytes + 255) & ~(size_t)255; return p;
    };
    float* Y       = (float*)take((size_t)N*128*4);
    float* A       = (float*)take((size_t)N*128*4);
    float* B       = (float*)take((size_t)N*128*4);
    float* HJK     = (float*)take((size_t)N*128*4);
    float* dinv    = (float*)take((size_t)N*4);
    int*   deg     = (int*)  take((size_t)N*4);
    int*   cursor  = (int*)  take((size_t)N*4);
    int*   row_start=(int*)  take((size_t)(N+1)*4);
    int*   csr_src = (int*)  take((size_t)E*4);
    float* pooled  = (float*)take((size_t)512*128*4);
    int*   partials= (int*)  take((size_t)512*4);

    hipMemsetAsync(deg,    0, (size_t)N*4, stream);
    hipMemsetAsync(cursor, 0, (size_t)N*4, stream);
    hipMemsetAsync(pooled, 0, (size_t)512*128*4, stream);

    int nb = (N + 255)/256;
    hist_kernel    <<<(E+255)/256, 256, 0, stream>>>(dst, E, deg);
    scan_part      <<<nb, 256, 0, stream>>>(deg, N, partials);
    scan_partials_k<<<1, 512, 0, stream>>>(partials, nb);
    scan_final     <<<nb, 256, 0, stream>>>(deg, N, partials, row_start);
    dinv_kernel    <<<nb, 256, 0, stream>>>(deg, dinv, N);
    fill_csr       <<<(E+255)/256, 256, 0, stream>>>(src, dst, E, row_start, cursor, csr_src);

    int gb = (N + 15)/16;
    int ab = (N + 3)/4;

    // layer 1
    gemm128<true ,false,false><<<gb, 256, 0, stream>>>(x, W0, nullptr, dinv, Y, N);
    aggregate<<<ab, 256, 0, stream>>>(Y, row_start, csr_src, dinv, b0, A, N);
    gemm128<false,false,true ><<<gb, 256, 0, stream>>>(A, Wjk,             bjk,    nullptr, HJK, N);
    // layer 2
    gemm128<true ,false,false><<<gb, 256, 0, stream>>>(A, W1, nullptr, dinv, Y, N);
    aggregate<<<ab, 256, 0, stream>>>(Y, row_start, csr_src, dinv, b1, B, N);
    gemm128<false,true ,false><<<gb, 256, 0, stream>>>(B, Wjk + 128*128,   nullptr, nullptr, HJK, N);
    // layer 3
    gemm128<true ,false,false><<<gb, 256, 0, stream>>>(B, W2, nullptr, dinv, Y, N);
    aggregate<<<ab, 256, 0, stream>>>(Y, row_start, csr_src, dinv, b2, A, N);
    gemm128<false,true ,false><<<gb, 256, 0, stream>>>(A, Wjk + 2*128*128, nullptr, nullptr, HJK, N);

    pool_kernel<<<(N+127)/128, 128, 0, stream>>>(HJK, batch, N, pooled);
    head_kernel<<<512, 128, 0, stream>>>(pooled, Wm1, bm1, Wm2, bm2, (float*)d_out);
}

// Round 2
// 953.397 us; speedup vs baseline: 1.2973x; 1.2973x over previous
//
#include <hip/hip_runtime.h>

typedef __attribute__((ext_vector_type(8))) short bf16x8;
typedef __attribute__((ext_vector_type(4))) float f32x4;

// ---------------- CSR build ----------------

__global__ void hist_kernel(const int* __restrict__ dst, int E, int* __restrict__ deg){
    int e = blockIdx.x*256 + threadIdx.x;
    if(e < E) atomicAdd(&deg[dst[e]], 1);
}

__global__ void scan_part(const int* __restrict__ deg, int n, int* __restrict__ partials){
    __shared__ int sm[256];
    int t = threadIdx.x;
    int idx = blockIdx.x*256 + t;
    sm[t] = (idx < n) ? deg[idx] : 0;
    __syncthreads();
    for(int s = 128; s > 0; s >>= 1){ if(t < s) sm[t] += sm[t+s]; __syncthreads(); }
    if(t == 0) partials[blockIdx.x] = sm[0];
}

__global__ void scan_partials_k(int* __restrict__ partials, int nb){
    __shared__ int sm[512];
    int t = threadIdx.x;
    int orig = (t < nb) ? partials[t] : 0;
    sm[t] = orig; __syncthreads();
    for(int s = 1; s < 512; s <<= 1){
        int add = (t >= s) ? sm[t-s] : 0;
        __syncthreads();
        sm[t] += add;
        __syncthreads();
    }
    if(t < nb) partials[t] = sm[t] - orig;   // exclusive
}

__global__ void scan_final(const int* __restrict__ deg, int n,
                           const int* __restrict__ partials, int* __restrict__ row_start){
    __shared__ int sm[256];
    int t = threadIdx.x;
    int idx = blockIdx.x*256 + t;
    int orig = (idx < n) ? deg[idx] : 0;
    sm[t] = orig; __syncthreads();
    for(int s = 1; s < 256; s <<= 1){
        int add = (t >= s) ? sm[t-s] : 0;
        __syncthreads();
        sm[t] += add;
        __syncthreads();
    }
    int excl = partials[blockIdx.x] + sm[t] - orig;
    if(idx < n) row_start[idx] = excl;
    if(idx == n-1) row_start[n] = excl + orig;   // == E
}

__global__ void dinv_kernel(const int* __restrict__ deg, float* __restrict__ dinv, int n){
    int i = blockIdx.x*256 + threadIdx.x;
    if(i < n) dinv[i] = rsqrtf((float)deg[i] + 1.0f);
}

__global__ void fill_csr(const int* __restrict__ src, const int* __restrict__ dst, int E,
                         const int* __restrict__ row_start, int* __restrict__ cursor,
                         int* __restrict__ csr_src){
    int e = blockIdx.x*256 + threadIdx.x;
    if(e < E){
        int d = dst[e];
        int p = atomicAdd(&cursor[d], 1);
        csr_src[row_start[d] + p] = src[e];
    }
}

// ---------------- weight prep: f32 [128,128] -> transposed bf16 hi/lo [col][k] ----------------

__device__ inline void split_bf16(float x, unsigned short& h, unsigned short& l){
    union { float f; unsigned int u; } cv;
    cv.f = x;
    unsigned int u = cv.u;
    unsigned int rh = u + 0x7fffu + ((u >> 16) & 1u);
    h = (unsigned short)(rh >> 16);
    union { unsigned int u; float f; } hb;
    hb.u = ((unsigned int)h) << 16;
    float r = x - hb.f;
    cv.f = r;
    unsigned int u2 = cv.u;
    unsigned int rl = u2 + 0x7fffu + ((u2 >> 16) & 1u);
    l = (unsigned short)(rl >> 16);
}

__global__ void prep_w_all(const float* __restrict__ W0, const float* __restrict__ W1,
                           const float* __restrict__ W2, const float* __restrict__ Wjk,
                           unsigned short* __restrict__ hi, unsigned short* __restrict__ lo){
    int m = blockIdx.x >> 6;                         // 0..5
    int i = (blockIdx.x & 63)*256 + threadIdx.x;     // 0..16383
    const float* W = (m==0) ? W0 : (m==1) ? W1 : (m==2) ? W2 : (Wjk + (m-3)*16384);
    int k = i >> 7, c = i & 127;
    unsigned short h, l;
    split_bf16(W[i], h, l);
    hi[m*16384 + c*128 + k] = h;
    lo[m*16384 + c*128 + k] = l;
}

// ---------------- MFMA GEMM: out[n,128] = in[n,128] @ W (+bias)(+acc)(*dinv_row) ----------------
// W supplied as transposed bf16 hi/lo: Wt[c][k]. Split 3-MFMA scheme for ~f32 accuracy.
// A frag (16x16x32): lane holds A[lane&15][(lane>>4)*8 + j], j=0..7 (contiguous k)
// C/D: col = lane&15, row = (lane>>4)*4 + reg   [m89-verified]

template<bool SCALE, bool ACC, bool BIAS>
__global__ __launch_bounds__(256) void gemm_mfma(const float* __restrict__ in,
                                                 const unsigned short* __restrict__ Wt_hi,
                                                 const unsigned short* __restrict__ Wt_lo,
                                                 const float* __restrict__ bias,
                                                 const float* __restrict__ dinv,
                                                 float* __restrict__ out, int n){
    int t = threadIdx.x;
    int wave = t >> 6, lane = t & 63;
    int r0 = blockIdx.x*64 + wave*16;
    if(r0 >= n) return;                  // n % 16 == 0, so valid waves are fully in-bounds
    int lr = lane & 15;                  // A-row / B-col / C-col
    int lk = (lane >> 4) * 8;            // k base for A/B frags

    f32x4 acc[8];
    #pragma unroll
    for(int c = 0; c < 8; ++c) acc[c] = (f32x4){0.f, 0.f, 0.f, 0.f};

    const float* arow = in + (size_t)(r0 + lr)*128;
    const unsigned short* bh = Wt_hi + lr*128 + lk;
    const unsigned short* bl = Wt_lo + lr*128 + lk;

    #pragma unroll
    for(int k0 = 0; k0 < 128; k0 += 32){
        f32x4 a0 = *(const f32x4*)(arow + k0 + lk);
        f32x4 a1 = *(const f32x4*)(arow + k0 + lk + 4);
        bf16x8 ahi, alo;
        #pragma unroll
        for(int j = 0; j < 4; ++j){
            unsigned short h, l;
            split_bf16(a0[j], h, l);
            ahi[j] = (short)h; alo[j] = (short)l;
            split_bf16(a1[j], h, l);
            ahi[j+4] = (short)h; alo[j+4] = (short)l;
        }
        #pragma unroll
        for(int c = 0; c < 8; ++c){
            bf16x8 bhi = *(const bf16x8*)(bh + c*2048 + k0);
            bf16x8 blo = *(const bf16x8*)(bl + c*2048 + k0);
            acc[c] = __builtin_amdgcn_mfma_f32_16x16x32_bf16(ahi, bhi, acc[c], 0, 0, 0);
            acc[c] = __builtin_amdgcn_mfma_f32_16x16x32_bf16(alo, bhi, acc[c], 0, 0, 0);
            acc[c] = __builtin_amdgcn_mfma_f32_16x16x32_bf16(ahi, blo, acc[c], 0, 0, 0);
        }
    }

    float dv[4];
    #pragma unroll
    for(int i = 0; i < 4; ++i){
        int crow = r0 + ((lane >> 4) << 2) + i;
        dv[i] = SCALE ? dinv[crow] : 1.f;
    }
    #pragma unroll
    for(int c = 0; c < 8; ++c){
        int ccol = c*16 + lr;
        float bcol = BIAS ? bias[ccol] : 0.f;
        #pragma unroll
        for(int i = 0; i < 4; ++i){
            int crow = r0 + ((lane >> 4) << 2) + i;
            float v = acc[c][i];
            if(BIAS) v += bcol;
            if(SCALE) v *= dv[i];
            if(ACC) v += out[(size_t)crow*128 + ccol];
            out[(size_t)crow*128 + ccol] = v;
        }
    }
}

// ---------------- pull aggregation: h[n] = relu(dinv[n]*(y[n] + sum_src y[src]) + b) ----------------
// 4-way unrolled gather (4 independent accumulators) + predicated tail -> 4+ loads in flight.

__global__ __launch_bounds__(256) void aggregate(const float* __restrict__ y, const int* __restrict__ row_start,
                                                 const int* __restrict__ csr_src, const float* __restrict__ dinv,
                                                 const float* __restrict__ bias, float* __restrict__ hout, int n){
    int wave = threadIdx.x >> 6;
    int lane = threadIdx.x & 63;
    int node = blockIdx.x*4 + wave;
    if(node >= n) return;
    const float2* __restrict__ y2 = (const float2*)y;
    int s0 = row_start[node];
    int s1 = row_start[node+1];

    float2 self = y2[(size_t)node*64 + lane];     // self term (already *dinv[node])
    float ax0 = self.x, ay0 = self.y;
    float ax1 = 0.f, ay1 = 0.f, ax2 = 0.f, ay2 = 0.f, ax3 = 0.f, ay3 = 0.f;

    int j = s0;
    for(; j + 4 <= s1; j += 4){
        int i0 = csr_src[j+0];
        int i1 = csr_src[j+1];
        int i2 = csr_src[j+2];
        int i3 = csr_src[j+3];
        float2 v0 = y2[(size_t)i0*64 + lane];
        float2 v1 = y2[(size_t)i1*64 + lane];
        float2 v2 = y2[(size_t)i2*64 + lane];
        float2 v3 = y2[(size_t)i3*64 + lane];
        ax0 += v0.x; ay0 += v0.y;
        ax1 += v1.x; ay1 += v1.y;
        ax2 += v2.x; ay2 += v2.y;
        ax3 += v3.x; ay3 += v3.y;
    }
    int rem = s1 - j;                              // 0..3, predicated tail (no serial loop)
    int i0 = (rem > 0) ? csr_src[j+0] : node;
    int i1 = (rem > 1) ? csr_src[j+1] : node;
    int i2 = (rem > 2) ? csr_src[j+2] : node;
    float2 v0 = y2[(size_t)i0*64 + lane];
    float2 v1 = y2[(size_t)i1*64 + lane];
    float2 v2 = y2[(size_t)i2*64 + lane];
    if(rem > 0){ ax0 += v0.x; ay0 += v0.y; }
    if(rem > 1){ ax1 += v1.x; ay1 += v1.y; }
    if(rem > 2){ ax2 += v2.x; ay2 += v2.y; }

    float dn = dinv[node];
    float bx = bias[lane*2], by = bias[lane*2+1];
    float2 r;
    r.x = fmaxf(fmaf((ax0 + ax1) + (ax2 + ax3), dn, bx), 0.f);
    r.y = fmaxf(fmaf((ay0 + ay1) + (ay2 + ay3), dn, by), 0.f);
    *(float2*)&hout[(size_t)node*128 + lane*2] = r;
}

// ---------------- pooling over sorted batch ----------------

__global__ void pool_kernel(const float* __restrict__ hjk, const int* __restrict__ batch,
                            int n, float* __restrict__ pooled){
    int c = threadIdx.x;          // 128 threads = columns
    int base = blockIdx.x*128;
    int end = base + 128; if(end > n) end = n;
    float acc = 0.f; int cur = -1;
    for(int i = base; i < end; ++i){
        int g = batch[i];
        if(g != cur){
            if(cur >= 0) atomicAdd(&pooled[cur*128 + c], acc);
            cur = g; acc = 0.f;
        }
        acc += hjk[(size_t)i*128 + c];
    }
    if(cur >= 0) atomicAdd(&pooled[cur*128 + c], acc);
}

// ---------------- MLP head ----------------

__global__ void head_kernel(const float* __restrict__ pooled,
                            const float* __restrict__ Wm1, const float* __restrict__ bm1,
                            const float* __restrict__ Wm2, const float* __restrict__ bm2,
                            float* __restrict__ out){
    __shared__ float p[128];
    __shared__ float tq[128];
    int g = blockIdx.x, j = threadIdx.x;
    p[j] = pooled[g*128 + j];
    __syncthreads();
    float a = bm1[j];
    for(int k = 0; k < 128; ++k) a = fmaf(p[k], Wm1[k*128 + j], a);
    tq[j] = fmaxf(a, 0.f);
    __syncthreads();
    if(j < 10){
        float o = bm2[j];
        for(int k = 0; k < 128; ++k) o = fmaf(tq[k], Wm2[k*10 + j], o);
        out[g*10 + j] = o;
    }
}

// ---------------- launch ----------------

extern "C" void kernel_launch(void* const* d_in, const int* in_sizes, int n_in,
                              void* d_out, int out_size, void* d_ws, size_t ws_size,
                              hipStream_t stream){
    const float* x    = (const float*)d_in[0];
    const int*   ei   = (const int*)  d_in[1];
    const int*   batch= (const int*)  d_in[2];
    const float* W0   = (const float*)d_in[3];
    const float* b0   = (const float*)d_in[4];
    const float* W1   = (const float*)d_in[5];
    const float* b1   = (const float*)d_in[6];
    const float* W2   = (const float*)d_in[7];
    const float* b2   = (const float*)d_in[8];
    const float* Wjk  = (const float*)d_in[9];
    const float* bjk  = (const float*)d_in[10];
    const float* Wm1  = (const float*)d_in[11];
    const float* bm1  = (const float*)d_in[12];
    const float* Wm2  = (const float*)d_in[13];
    const float* bm2  = (const float*)d_in[14];

    const int N = in_sizes[0] / 128;
    const int E = in_sizes[1] / 2;
    const int* src = ei;
    const int* dst = ei + E;

    char* ws = (char*)d_ws;
    size_t off = 0;
    auto take = [&](size_t bytes)->char*{
        char* p = ws + off; off = (off + bytes + 255) & ~(size_t)255; return p;
    };
    float* Y       = (float*)take((size_t)N*128*4);
    float* A       = (float*)take((size_t)N*128*4);
    float* B       = (float*)take((size_t)N*128*4);
    float* HJK     = (float*)take((size_t)N*128*4);
    float* dinv    = (float*)take((size_t)N*4);
    int*   deg     = (int*)  take((size_t)N*4);
    int*   cursor  = (int*)  take((size_t)N*4);
    int*   row_start=(int*)  take((size_t)(N+1)*4);
    int*   csr_src = (int*)  take((size_t)E*4);
    float* pooled  = (float*)take((size_t)512*128*4);
    int*   partials= (int*)  take((size_t)512*4);
    unsigned short* Whi = (unsigned short*)take((size_t)6*16384*2);
    unsigned short* Wlo = (unsigned short*)take((size_t)6*16384*2);

    hipMemsetAsync(deg,    0, (size_t)N*4, stream);
    hipMemsetAsync(cursor, 0, (size_t)N*4, stream);
    hipMemsetAsync(pooled, 0, (size_t)512*128*4, stream);

    int nb = (N + 255)/256;
    hist_kernel    <<<(E+255)/256, 256, 0, stream>>>(dst, E, deg);
    scan_part      <<<nb, 256, 0, stream>>>(deg, N, partials);
    scan_partials_k<<<1, 512, 0, stream>>>(partials, nb);
    scan_final     <<<nb, 256, 0, stream>>>(deg, N, partials, row_start);
    dinv_kernel    <<<nb, 256, 0, stream>>>(deg, dinv, N);
    fill_csr       <<<(E+255)/256, 256, 0, stream>>>(src, dst, E, row_start, cursor, csr_src);
    prep_w_all     <<<384, 256, 0, stream>>>(W0, W1, W2, Wjk, Whi, Wlo);

    int gb = (N + 63)/64;
    int ab = (N + 3)/4;

    // layer 1
    gemm_mfma<true ,false,false><<<gb, 256, 0, stream>>>(x, Whi,           Wlo,           nullptr, dinv, Y, N);
    aggregate<<<ab, 256, 0, stream>>>(Y, row_start, csr_src, dinv, b0, A, N);
    gemm_mfma<false,false,true ><<<gb, 256, 0, stream>>>(A, Whi + 3*16384, Wlo + 3*16384, bjk, nullptr, HJK, N);
    // layer 2
    gemm_mfma<true ,false,false><<<gb, 256, 0, stream>>>(A, Whi + 1*16384, Wlo + 1*16384, nullptr, dinv, Y, N);
    aggregate<<<ab, 256, 0, stream>>>(Y, row_start, csr_src, dinv, b1, B, N);
    gemm_mfma<false,true ,false><<<gb, 256, 0, stream>>>(B, Whi + 4*16384, Wlo + 4*16384, nullptr, nullptr, HJK, N);
    // layer 3
    gemm_mfma<true ,false,false><<<gb, 256, 0, stream>>>(B, Whi + 2*16384, Wlo + 2*16384, nullptr, dinv, Y, N);
    aggregate<<<ab, 256, 0, stream>>>(Y, row_start, csr_src, dinv, b2, A, N);
    gemm_mfma<false,true ,false><<<gb, 256, 0, stream>>>(A, Whi + 5*16384, Wlo + 5*16384, nullptr, nullptr, HJK, N);

    pool_kernel<<<(N+127)/128, 128, 0, stream>>>(HJK, batch, N, pooled);
    head_kernel<<<512, 128, 0, stream>>>(pooled, Wm1, bm1, Wm2, bm2, (float*)d_out);
}